// Round 12
// baseline (707.364 us; speedup 1.0000x reference)
//
#include <hip/hip_runtime.h>
#include <hip/hip_bf16.h>

// AgreementRouting, single NORMAL-launch fused kernel. B=128, IC=1152,
// OC=10, D=16, 3 iters, f32 in/out.
//
// 1024 blocks x 256 thr, __launch_bounds__(256,4): 4 blocks/CU co-resident
// by construction (grid = 4x256). 8 parts per b (part=bid&7), 144 slices each.
//
// P0: stream f32 u ONCE (94.4MB, non-temporal) -> s0 partials + bf16 u16 copy
//     (47.2MB). Phases 1..3: each part re-reads ITS OWN u16 quarter (XCD-local
//     L2/L3; no cross-block visibility needed) with a 2-stage pipelined loop.
//     Logits: bb_T = b_in + <u, sum_{t<T} v_t> (linearity, R2-proven).
//
// R11 lessons applied: register-resident u is DEAD (allocator caps at 128
// VGPR and spills 90-dword arrays -> 103MB scratch traffic). Live set here
// ~60 regs. Sync = R11-PROVEN tag barriers: slot[b][part] release-stores
// phase-unique tag TAGP(T)=0x51C0000T; waiters equality-poll all 8 slots.
// Entry garbage (0xAA poison / stale TAG4) never equals awaited tag -> no
// init kernel, deterministic under graph replay.
//
// Lane scheme per 16-lane group (slice = 10x16 f32): l=tid&15, h=l>>3.
// Lane owns (j=2k+h, d=2(l&7)..2(l&7)+1), k=0..4 == float offset 32k+2l.
// Cross-lane in hot loops: all DPP (VALU pipe), R6-proven.

#define B_     128
#define IC_    1152
#define OC_    10
#define ROW_   160
#define WPS_   80      // bf16 dwords per slice
#define PARTS_ 8
#define SPB_   144     // slices per part
#define UPB_   9       // slices per 16-lane group
#define GSTR_  128     // dwords per b's slot array (8 slots x 16 dwords)
#define TAGP(p) (0x51C00000u + (uint32_t)(p))

typedef float v2f __attribute__((ext_vector_type(2)));

__device__ __forceinline__ float bf_lo(uint32_t w) { return __uint_as_float(w << 16); }
__device__ __forceinline__ float bf_hi(uint32_t w) { return __uint_as_float(w & 0xffff0000u); }

template<int CTRL>
__device__ __forceinline__ float dppf(float x) {
    return __int_as_float(__builtin_amdgcn_update_dpp(
        0, __float_as_int(x), CTRL, 0xF, 0xF, true));
}
__device__ __forceinline__ float dpp_sum8(float x) {
    x += dppf<0xB1>(x);    // quad_perm [1,0,3,2]  (xor1)
    x += dppf<0x4E>(x);    // quad_perm [2,3,0,1]  (xor2)
    x += dppf<0x141>(x);   // row_half_mirror      (cross-quad within 8)
    return x;
}
__device__ __forceinline__ float softmax10(float own[5]) {
    float m = own[0];
#pragma unroll
    for (int k = 1; k < 5; ++k) m = fmaxf(m, own[k]);
    m = fmaxf(m, dppf<0x128>(m));          // row_ror:8 == xor8 within 16
    float sum = 0.f;
#pragma unroll
    for (int k = 0; k < 5; ++k) { own[k] = __expf(own[k] - m); sum += own[k]; }
    sum += dppf<0x128>(sum);
    return 1.f / sum;
}

__device__ __forceinline__ float agent_loadf(const float* p) {
    return __hip_atomic_load(p, __ATOMIC_RELAXED, __HIP_MEMORY_SCOPE_AGENT);
}
__device__ __forceinline__ void agent_storef(float* p, float v) {
    __hip_atomic_store(p, v, __ATOMIC_RELAXED, __HIP_MEMORY_SCOPE_AGENT);
}

__device__ __forceinline__ void gbar(uint32_t* gslots, int tid, int part, uint32_t tag) {
    __threadfence();
    __syncthreads();
    if (tid == 0)
        __hip_atomic_store(&gslots[part * 16], tag, __ATOMIC_RELEASE, __HIP_MEMORY_SCOPE_AGENT);
    if (tid < PARTS_)
        while (__hip_atomic_load(&gslots[tid * 16], __ATOMIC_ACQUIRE, __HIP_MEMORY_SCOPE_AGENT) != tag)
            __builtin_amdgcn_s_sleep(2);
    __syncthreads();
}

__global__ __launch_bounds__(256, 4) void routing_kernel(
    const float* __restrict__ u, const float* __restrict__ b_in,
    uint32_t* __restrict__ slots, float* __restrict__ s_part,
    uint32_t* __restrict__ u16, float* __restrict__ out)
{
    const int bid = blockIdx.x, tid = threadIdx.x;
    const int l = tid & 15, h = l >> 3, g = tid >> 4;
    const int b = bid >> 3, part = bid & 7;
    const int wave = tid >> 6, lane = tid & 63;
    uint32_t* gslots = slots + b * GSTR_;

    __shared__ float red[4][ROW_];
    __shared__ float v_lds[ROW_];
    __shared__ float b_lds[SPB_ * OC_];   // 5.76 KB, this part's b_in rows

    // stage this part's b_in rows (1440 contiguous floats)
#pragma unroll
    for (int it = 0; it < 6; ++it) {
        int idx = it * 256 + tid;
        if (idx < SPB_ * OC_) b_lds[idx] = b_in[part * SPB_ * OC_ + idx];
    }
    __syncthreads();

    // ---------------- P0: f32 u -> s0 partial + bf16 u16 copy ----------------
    {
        float2 sc[5];
#pragma unroll
        for (int k = 0; k < 5; ++k) { sc[k].x = 0.f; sc[k].y = 0.f; }
#pragma unroll
        for (int uu = 0; uu < UPB_; ++uu) {
            const int su = uu * 16 + g;
            const int i  = part * SPB_ + su;
            const v2f* up = (const v2f*)(u + (size_t)(b * IC_ + i) * ROW_ + 2 * l);
            v2f uv[5];
#pragma unroll
            for (int k = 0; k < 5; ++k) uv[k] = __builtin_nontemporal_load(up + 16 * k);

            uint32_t* wp = u16 + (size_t)(b * IC_ + i) * WPS_;
#pragma unroll
            for (int k = 0; k < 5; ++k) {
                __hip_bfloat16 bx = __float2bfloat16(uv[k].x);
                __hip_bfloat16 by = __float2bfloat16(uv[k].y);
                wp[16 * k + l] = ((uint32_t)(*(const uint16_t*)&by) << 16) |
                                  (uint32_t)(*(const uint16_t*)&bx);
            }
            float own[5];
#pragma unroll
            for (int k = 0; k < 5; ++k) own[k] = b_lds[su * OC_ + 2 * k + h];
            const float inv = softmax10(own);
#pragma unroll
            for (int k = 0; k < 5; ++k) {
                float c = own[k] * inv;
                sc[k].x += c * uv[k].x; sc[k].y += c * uv[k].y;
            }
        }
#pragma unroll
        for (int k = 0; k < 5; ++k) {
            sc[k].x += __shfl_xor(sc[k].x, 16); sc[k].y += __shfl_xor(sc[k].y, 16);
            sc[k].x += __shfl_xor(sc[k].x, 32); sc[k].y += __shfl_xor(sc[k].y, 32);
        }
        if (lane < 16) {
#pragma unroll
            for (int k = 0; k < 5; ++k)
                *(float2*)&red[wave][32 * k + 2 * l] = sc[k];
        }
        __syncthreads();
        if (tid < ROW_) {
            float t = red[0][tid] + red[1][tid] + red[2][tid] + red[3][tid];
            agent_storef(&s_part[((size_t)(0 * B_ + b) * PARTS_ + part) * ROW_ + tid], t);
        }
        gbar(gslots, tid, part, TAGP(1));
    }

    // ---------------- phases 1..3: re-read own u16 quarter ----------------
    float vsum = 0.f;          // valid for tid<ROW_
    for (int T = 1; T <= 3; ++T) {
        if (tid < ROW_) {
            const float* sp = s_part + ((size_t)((T - 1) * B_ + b) * PARTS_) * ROW_;
            float x = 0.f;
#pragma unroll
            for (int p = 0; p < PARTS_; ++p) x += agent_loadf(sp + p * ROW_ + tid);
            float sq = x * x;
            sq += __shfl_xor(sq, 1, 16);
            sq += __shfl_xor(sq, 2, 16);
            sq += __shfl_xor(sq, 4, 16);
            sq += __shfl_xor(sq, 8, 16);
            vsum += (sq / (1.f + sq)) * x * rsqrtf(sq + 1e-8f);
            v_lds[tid] = vsum;
        }
        __syncthreads();

        float2 vv[5];
#pragma unroll
        for (int k = 0; k < 5; ++k)
            vv[k] = *(const float2*)&v_lds[32 * k + 2 * l];

        float2 sc[5];
#pragma unroll
        for (int k = 0; k < 5; ++k) { sc[k].x = 0.f; sc[k].y = 0.f; }

#define B_LOAD(UW, uu) do {                                                 \
        const int su_ = (uu) * 16 + g;                                      \
        const uint32_t* wp_ = u16 + (size_t)(b * IC_ + part * SPB_ + su_) * WPS_; \
        _Pragma("unroll")                                                   \
        for (int k = 0; k < 5; ++k) UW[k] = wp_[16 * k + l];                \
    } while (0)

#define B_COMP(UW, uu) do {                                                 \
        const int su_ = (uu) * 16 + g;                                      \
        float own[5];                                                       \
        _Pragma("unroll")                                                   \
        for (int k = 0; k < 5; ++k) own[k] = b_lds[su_ * OC_ + 2 * k + h];  \
        _Pragma("unroll")                                                   \
        for (int k = 0; k < 5; ++k) {                                       \
            float pd = bf_lo(UW[k]) * vv[k].x + bf_hi(UW[k]) * vv[k].y;     \
            own[k] += dpp_sum8(pd);                                         \
        }                                                                   \
        const float inv = softmax10(own);                                   \
        _Pragma("unroll")                                                   \
        for (int k = 0; k < 5; ++k) {                                       \
            float c = own[k] * inv;                                         \
            sc[k].x += c * bf_lo(UW[k]); sc[k].y += c * bf_hi(UW[k]);       \
        }                                                                   \
    } while (0)

        uint32_t uwA[5], uwB[5];
        B_LOAD(uwA, 0);
#pragma clang loop unroll(disable)
        for (int uu = 0; uu < UPB_ - 1; uu += 2) {
            B_LOAD(uwB, uu + 1);
            B_COMP(uwA, uu);
            if (uu + 2 < UPB_) B_LOAD(uwA, uu + 2);
            B_COMP(uwB, uu + 1);
        }
        B_COMP(uwA, UPB_ - 1);
#undef B_LOAD
#undef B_COMP

#pragma unroll
        for (int k = 0; k < 5; ++k) {
            sc[k].x += __shfl_xor(sc[k].x, 16); sc[k].y += __shfl_xor(sc[k].y, 16);
            sc[k].x += __shfl_xor(sc[k].x, 32); sc[k].y += __shfl_xor(sc[k].y, 32);
        }
        if (lane < 16) {
#pragma unroll
            for (int k = 0; k < 5; ++k)
                *(float2*)&red[wave][32 * k + 2 * l] = sc[k];
        }
        __syncthreads();
        if (tid < ROW_) {
            float t = red[0][tid] + red[1][tid] + red[2][tid] + red[3][tid];
            agent_storef(&s_part[((size_t)(T * B_ + b) * PARTS_ + part) * ROW_ + tid], t);
        }

        if (T < 3) {
            gbar(gslots, tid, part, TAGP(T + 1));
        } else {
            // final: all arrive; part 0 waits, reduces, squashes, writes out
            __threadfence();
            __syncthreads();
            if (tid == 0)
                __hip_atomic_store(&gslots[part * 16], TAGP(4),
                                   __ATOMIC_RELEASE, __HIP_MEMORY_SCOPE_AGENT);
            if (part == 0) {
                if (tid < PARTS_)
                    while (__hip_atomic_load(&gslots[tid * 16], __ATOMIC_ACQUIRE,
                                             __HIP_MEMORY_SCOPE_AGENT) != TAGP(4))
                        __builtin_amdgcn_s_sleep(2);
                __syncthreads();
                if (tid < ROW_) {
                    const float* sp = s_part + ((size_t)(3 * B_ + b) * PARTS_) * ROW_;
                    float x = 0.f;
#pragma unroll
                    for (int p = 0; p < PARTS_; ++p) x += agent_loadf(sp + p * ROW_ + tid);
                    float sq = x * x;
                    sq += __shfl_xor(sq, 1, 16);
                    sq += __shfl_xor(sq, 2, 16);
                    sq += __shfl_xor(sq, 4, 16);
                    sq += __shfl_xor(sq, 8, 16);
                    out[b * ROW_ + tid] = (sq / (1.f + sq)) * x * rsqrtf(sq + 1e-8f);
                }
            }
        }
    }
}

extern "C" void kernel_launch(void* const* d_in, const int* in_sizes, int n_in,
                              void* d_out, int out_size, void* d_ws, size_t ws_size,
                              hipStream_t stream) {
    const float* u    = (const float*)d_in[0];
    const float* b_in = (const float*)d_in[1];
    float* out = (float*)d_out;

    uint32_t* slots  = (uint32_t*)d_ws;                    // 128*128 dwords = 64 KB
    float*    s_part = (float*)(slots + B_ * GSTR_);       // 4*128*8*160 f32 = 2.62 MB
    uint32_t* u16    = (uint32_t*)(s_part + 4 * B_ * PARTS_ * ROW_); // 47.2 MB

    routing_kernel<<<dim3(B_ * PARTS_), dim3(256), 0, stream>>>(
        u, b_in, slots, s_part, u16, out);
}

// Round 13
// 71.430 us; speedup vs baseline: 9.9029x; 9.9029x over previous
//
#include <hip/hip_runtime.h>
#include <hip/hip_bf16.h>

// AgreementRouting, 5-kernel full-machine plan. B=128, IC=1152, OC=10, D=16,
// 3 iters, f32 in/out.
//
// R12 lesson (3x-confirmed): in-kernel cross-block sync costs ~200us/phase on
// MI355X (agent-scope release/acquire = L2 writeback/invalidate storms across
// non-coherent per-XCD L2s). Kernel boundaries are the cheap global sync.
//
// A  (1024x256): stream f32 u ONCE -> u16 bf16 copy + s0 partials (8/b).
// I<T>(1024x256): recompute vsum = sum_{t<T} squash(reduce s_t partials)
//                 (tiny), then stream OWN u16 quarter -> s_T partials.
//                 Logits: bb_T = b_in + <u, vsum> (linearity, R2-proven).
//                 Same grid shape as A -> same block->XCD map -> L2 locality.
// F  (80x256): reduce s3 partials + squash -> out.
//
// No atomics, no barriers, no spill; all ws state rewritten every launch.
//
// Lane scheme per 16-lane group (slice = 10x16 f32): l=tid&15, h=l>>3.
// Lane owns (j=2k+h, d=2(l&7)..2(l&7)+1), k=0..4 == float offset 32k+2l.
// Cross-lane in hot loops: all DPP (VALU pipe), R6-proven.

#define B_     128
#define IC_    1152
#define OC_    10
#define ROW_   160
#define WPS_   80      // bf16 dwords per slice
#define PARTS_ 8
#define SPB_   144     // slices per part
#define UPB_   9       // slices per 16-lane group
#define SOUT_  20480   // B_*ROW_

typedef float v2f __attribute__((ext_vector_type(2)));

__device__ __forceinline__ float bf_lo(uint32_t w) { return __uint_as_float(w << 16); }
__device__ __forceinline__ float bf_hi(uint32_t w) { return __uint_as_float(w & 0xffff0000u); }

template<int CTRL>
__device__ __forceinline__ float dppf(float x) {
    return __int_as_float(__builtin_amdgcn_update_dpp(
        0, __float_as_int(x), CTRL, 0xF, 0xF, true));
}
__device__ __forceinline__ float dpp_sum8(float x) {
    x += dppf<0xB1>(x);    // quad_perm [1,0,3,2]  (xor1)
    x += dppf<0x4E>(x);    // quad_perm [2,3,0,1]  (xor2)
    x += dppf<0x141>(x);   // row_half_mirror      (cross-quad within 8)
    return x;
}
__device__ __forceinline__ float softmax10(float own[5]) {
    float m = own[0];
#pragma unroll
    for (int k = 1; k < 5; ++k) m = fmaxf(m, own[k]);
    m = fmaxf(m, dppf<0x128>(m));          // row_ror:8 == xor8 within 16
    float sum = 0.f;
#pragma unroll
    for (int k = 0; k < 5; ++k) { own[k] = __expf(own[k] - m); sum += own[k]; }
    sum += dppf<0x128>(sum);
    return 1.f / sum;
}

// ---------------- Kernel A ----------------
__global__ __launch_bounds__(256) void a_kernel(
    const float* __restrict__ u, const float* __restrict__ b_in,
    uint32_t* __restrict__ u16, float* __restrict__ s_part)
{
    const int bid = blockIdx.x, tid = threadIdx.x;
    const int l = tid & 15, h = l >> 3, g = tid >> 4;
    const int b = bid >> 3, part = bid & 7;
    const int wave = tid >> 6, lane = tid & 63;

    __shared__ float red[4][ROW_];
    __shared__ float b_lds[SPB_ * OC_];

#pragma unroll
    for (int it = 0; it < 6; ++it) {
        int idx = it * 256 + tid;
        if (idx < SPB_ * OC_) b_lds[idx] = b_in[part * SPB_ * OC_ + idx];
    }
    __syncthreads();

    float2 sc[5];
#pragma unroll
    for (int k = 0; k < 5; ++k) { sc[k].x = 0.f; sc[k].y = 0.f; }
#pragma unroll
    for (int uu = 0; uu < UPB_; ++uu) {
        const int su = uu * 16 + g;
        const int i  = part * SPB_ + su;
        const v2f* up = (const v2f*)(u + (size_t)(b * IC_ + i) * ROW_ + 2 * l);
        v2f uv[5];
#pragma unroll
        for (int k = 0; k < 5; ++k) uv[k] = __builtin_nontemporal_load(up + 16 * k);

        uint32_t* wp = u16 + (size_t)(b * IC_ + i) * WPS_;
#pragma unroll
        for (int k = 0; k < 5; ++k) {
            __hip_bfloat16 bx = __float2bfloat16(uv[k].x);
            __hip_bfloat16 by = __float2bfloat16(uv[k].y);
            wp[16 * k + l] = ((uint32_t)(*(const uint16_t*)&by) << 16) |
                              (uint32_t)(*(const uint16_t*)&bx);
        }
        float own[5];
#pragma unroll
        for (int k = 0; k < 5; ++k) own[k] = b_lds[su * OC_ + 2 * k + h];
        const float inv = softmax10(own);
#pragma unroll
        for (int k = 0; k < 5; ++k) {
            float c = own[k] * inv;
            sc[k].x += c * uv[k].x; sc[k].y += c * uv[k].y;
        }
    }
#pragma unroll
    for (int k = 0; k < 5; ++k) {
        sc[k].x += __shfl_xor(sc[k].x, 16); sc[k].y += __shfl_xor(sc[k].y, 16);
        sc[k].x += __shfl_xor(sc[k].x, 32); sc[k].y += __shfl_xor(sc[k].y, 32);
    }
    if (lane < 16) {
#pragma unroll
        for (int k = 0; k < 5; ++k)
            *(float2*)&red[wave][32 * k + 2 * l] = sc[k];
    }
    __syncthreads();
    if (tid < ROW_) {
        float t = red[0][tid] + red[1][tid] + red[2][tid] + red[3][tid];
        s_part[(size_t)((0 * B_ + b) * PARTS_ + part) * ROW_ + tid] = t;
    }
}

// ---------------- Kernel I<T> ----------------
template<int T>
__global__ __launch_bounds__(256) void i_kernel(
    const uint32_t* __restrict__ u16, const float* __restrict__ b_in,
    const float* __restrict__ s_part, float* __restrict__ s_next)
{
    const int bid = blockIdx.x, tid = threadIdx.x;
    const int l = tid & 15, h = l >> 3, g = tid >> 4;
    const int b = bid >> 3, part = bid & 7;
    const int wave = tid >> 6, lane = tid & 63;

    __shared__ float red[4][ROW_];
    __shared__ float v_lds[ROW_];
    __shared__ float b_lds[SPB_ * OC_];

#pragma unroll
    for (int it = 0; it < 6; ++it) {
        int idx = it * 256 + tid;
        if (idx < SPB_ * OC_) b_lds[idx] = b_in[part * SPB_ * OC_ + idx];
    }

    if (tid < ROW_) {
        float vsum = 0.f;
#pragma unroll
        for (int t = 0; t < T; ++t) {
            const float* sp = s_part + (size_t)((t * B_ + b) * PARTS_) * ROW_;
            float x = 0.f;
#pragma unroll
            for (int p = 0; p < PARTS_; ++p) x += sp[p * ROW_ + tid];
            float sq = x * x;
            sq += __shfl_xor(sq, 1, 16);
            sq += __shfl_xor(sq, 2, 16);
            sq += __shfl_xor(sq, 4, 16);
            sq += __shfl_xor(sq, 8, 16);
            vsum += (sq / (1.f + sq)) * x * rsqrtf(sq + 1e-8f);
        }
        v_lds[tid] = vsum;
    }
    __syncthreads();

    float2 vv[5];
#pragma unroll
    for (int k = 0; k < 5; ++k)
        vv[k] = *(const float2*)&v_lds[32 * k + 2 * l];

    float2 sc[5];
#pragma unroll
    for (int k = 0; k < 5; ++k) { sc[k].x = 0.f; sc[k].y = 0.f; }

#define B_LOAD(UW, uu) do {                                                 \
        const int su_ = (uu) * 16 + g;                                      \
        const uint32_t* wp_ = u16 + (size_t)(b * IC_ + part * SPB_ + su_) * WPS_; \
        _Pragma("unroll")                                                   \
        for (int k = 0; k < 5; ++k) UW[k] = wp_[16 * k + l];                \
    } while (0)

#define B_COMP(UW, uu) do {                                                 \
        const int su_ = (uu) * 16 + g;                                      \
        float own[5];                                                       \
        _Pragma("unroll")                                                   \
        for (int k = 0; k < 5; ++k) own[k] = b_lds[su_ * OC_ + 2 * k + h];  \
        _Pragma("unroll")                                                   \
        for (int k = 0; k < 5; ++k) {                                       \
            float pd = bf_lo(UW[k]) * vv[k].x + bf_hi(UW[k]) * vv[k].y;     \
            own[k] += dpp_sum8(pd);                                         \
        }                                                                   \
        const float inv = softmax10(own);                                   \
        _Pragma("unroll")                                                   \
        for (int k = 0; k < 5; ++k) {                                       \
            float c = own[k] * inv;                                         \
            sc[k].x += c * bf_lo(UW[k]); sc[k].y += c * bf_hi(UW[k]);       \
        }                                                                   \
    } while (0)

    uint32_t uwA[5], uwB[5];
    B_LOAD(uwA, 0);
#pragma clang loop unroll(disable)
    for (int uu = 0; uu < UPB_ - 1; uu += 2) {
        B_LOAD(uwB, uu + 1);
        B_COMP(uwA, uu);
        if (uu + 2 < UPB_) B_LOAD(uwA, uu + 2);
        B_COMP(uwB, uu + 1);
    }
    B_COMP(uwA, UPB_ - 1);
#undef B_LOAD
#undef B_COMP

#pragma unroll
    for (int k = 0; k < 5; ++k) {
        sc[k].x += __shfl_xor(sc[k].x, 16); sc[k].y += __shfl_xor(sc[k].y, 16);
        sc[k].x += __shfl_xor(sc[k].x, 32); sc[k].y += __shfl_xor(sc[k].y, 32);
    }
    if (lane < 16) {
#pragma unroll
        for (int k = 0; k < 5; ++k)
            *(float2*)&red[wave][32 * k + 2 * l] = sc[k];
    }
    __syncthreads();
    if (tid < ROW_) {
        float t = red[0][tid] + red[1][tid] + red[2][tid] + red[3][tid];
        s_next[(size_t)(b * PARTS_ + part) * ROW_ + tid] = t;
    }
}

// ---------------- Kernel F ----------------
__global__ __launch_bounds__(256) void f_kernel(
    const float* __restrict__ s_part, float* __restrict__ out)
{
    const int idx = blockIdx.x * 256 + threadIdx.x;   // 0..SOUT_-1
    const int b = idx / ROW_, r = idx % ROW_;
    const float* sp = s_part + (size_t)(b * PARTS_) * ROW_;
    float x = 0.f;
#pragma unroll
    for (int p = 0; p < PARTS_; ++p) x += sp[p * ROW_ + r];
    float sq = x * x;
    sq += __shfl_xor(sq, 1, 16);
    sq += __shfl_xor(sq, 2, 16);
    sq += __shfl_xor(sq, 4, 16);
    sq += __shfl_xor(sq, 8, 16);
    out[idx] = (sq / (1.f + sq)) * x * rsqrtf(sq + 1e-8f);
}

extern "C" void kernel_launch(void* const* d_in, const int* in_sizes, int n_in,
                              void* d_out, int out_size, void* d_ws, size_t ws_size,
                              hipStream_t stream) {
    const float* u    = (const float*)d_in[0];
    const float* b_in = (const float*)d_in[1];
    float* out = (float*)d_out;

    float*    s_part = (float*)d_ws;   // 4 phases * B*8*160 f32 = 2.62 MB
    uint32_t* u16    = (uint32_t*)(s_part + 4 * B_ * PARTS_ * ROW_); // 47.2 MB

    const dim3 blk(256);
    const dim3 grid(B_ * PARTS_);      // 1024

    a_kernel<<<grid, blk, 0, stream>>>(u, b_in, u16, s_part);
    i_kernel<1><<<grid, blk, 0, stream>>>(u16, b_in, s_part,
                                          s_part + (size_t)1 * B_ * PARTS_ * ROW_);
    i_kernel<2><<<grid, blk, 0, stream>>>(u16, b_in, s_part,
                                          s_part + (size_t)2 * B_ * PARTS_ * ROW_);
    i_kernel<3><<<grid, blk, 0, stream>>>(u16, b_in, s_part,
                                          s_part + (size_t)3 * B_ * PARTS_ * ROW_);
    f_kernel<<<dim3(SOUT_ / 256), blk, 0, stream>>>(
        s_part + (size_t)3 * B_ * PARTS_ * ROW_, out);
}